// Round 6
// baseline (589.952 us; speedup 1.0000x reference)
//
#include <hip/hip_runtime.h>
#include <cmath>

// Problem constants (B_SZ=2, L=2048, D=1024, N=16)
#define D_DIM 1024
#define N_DIM 16
#define KTOT  2049          // 2*D + 1 (concat axis)
#define WS_STRIDE 36        // per-(b,l) row in ws: B[16], C[16 unused], sd @32

typedef float v4f __attribute__((ext_vector_type(4)));

// ---------------------------------------------------------------------------
// Kernel 1: projections. One block (256 thr = 4 waves) per (b,l) token.
//   wave 0: B rows 0..7  (+ s_delta)      -> ws
//   wave 1: B rows 8..15                  -> ws
//   wave 2: C rows 0..7                   -> out[.., k=2048, 0..7]
//   wave 3: C rows 8..15                  -> out[.., k=2048, 8..15]
// (Round-5 post-mortem: fusing this into the expansion kernel was neutral;
//  the split version was marginally better, so we keep it.)
// ---------------------------------------------------------------------------
__global__ __launch_bounds__(256) void proj_kernel(
    const float* __restrict__ x, const float* __restrict__ W_b,
    const float* __restrict__ W_c, const float* __restrict__ W_delta,
    float* __restrict__ ws, float* __restrict__ out)
{
    const int bl   = blockIdx.x;
    const int tid  = threadIdx.x;
    const int wave = tid >> 6;
    const int lane = tid & 63;

    const float* xrow  = x + (size_t)bl * D_DIM;
    const float* Wbase = (wave < 2) ? W_b : W_c;
    const int rowbase  = (wave & 1) * 8;

    float acc[8] = {0.f,0.f,0.f,0.f,0.f,0.f,0.f,0.f};
    float sd = 0.f;

    #pragma unroll
    for (int i = 0; i < 4; ++i) {
        const int off = (lane + (i << 6)) << 2;      // float offset, 16B aligned
        const v4f xv = *(const v4f*)(xrow + off);
        #pragma unroll
        for (int r = 0; r < 8; ++r) {
            const v4f wv = *(const v4f*)(Wbase + (size_t)(rowbase + r) * D_DIM + off);
            acc[r] = fmaf(xv[0], wv[0], acc[r]);
            acc[r] = fmaf(xv[1], wv[1], acc[r]);
            acc[r] = fmaf(xv[2], wv[2], acc[r]);
            acc[r] = fmaf(xv[3], wv[3], acc[r]);
        }
        if (wave == 0) {
            const v4f wv = *(const v4f*)(W_delta + off);
            sd = fmaf(xv[0], wv[0], sd);
            sd = fmaf(xv[1], wv[1], sd);
            sd = fmaf(xv[2], wv[2], sd);
            sd = fmaf(xv[3], wv[3], sd);
        }
    }

    // full 64-lane xor-shuffle reduction
    #pragma unroll
    for (int r = 0; r < 8; ++r) {
        #pragma unroll
        for (int m = 32; m >= 1; m >>= 1)
            acc[r] += __shfl_xor(acc[r], m, 64);
    }
    if (wave == 0) {
        #pragma unroll
        for (int m = 32; m >= 1; m >>= 1)
            sd += __shfl_xor(sd, m, 64);
    }

    if (lane == 0) {
        if (wave < 2) {
            float* dst = ws + (size_t)bl * WS_STRIDE + rowbase;
            #pragma unroll
            for (int r = 0; r < 8; ++r) dst[r] = acc[r];
            if (wave == 0) ws[(size_t)bl * WS_STRIDE + 32] = sd;
        } else {
            // C goes straight into the k = 2*D slot of the output
            float* dst = out + ((size_t)bl * KTOT + 2 * D_DIM) * N_DIM + rowbase;
            #pragma unroll
            for (int r = 0; r < 8; ++r) dst[r] = acc[r];
        }
    }
}

// ---------------------------------------------------------------------------
// Kernel 2: expansion, restructured so every block is a SINGLE-stream writer
// with the exact shape of the 6.3 TB/s fillBuffer kernel.
//
// Grid = BL*32 blocks: blk -> (token bl, sid in {0:A_bar, 1:deltaB_x},
// chunk in 0..15). Each block covers 64 d-values x 16 n for ONE stream and
// emits one contiguous, monotone 4 KB NT burst (256 thr x float4).
//
// Round-5 analysis: the previous two-streams-per-thread layout (stores 16 MB
// apart, alternating) ran at 5.4 TB/s = 86% of the fill kernel's 6.33 TB/s
// on the same buffer — interleaved streams fragment write-combining. Cost of
// the split: Delta/exp duplicated across the sid pair (~12 µs VALU chip-wide,
// hidden) and x/A read twice (+17 MB ~ +2.7 µs).
//
// sid is block-uniform -> no divergence. Math unchanged (native exp/log/rcp,
// branchless Taylor fallback for |dA|<0.5).
// ---------------------------------------------------------------------------
__global__ __launch_bounds__(256) void ssm_kernel(
    const float* __restrict__ x, const float* __restrict__ A,
    const float* __restrict__ delta_param, const float* __restrict__ ws,
    float* __restrict__ out)
{
    const int blk   = blockIdx.x;
    const int bl    = blk >> 5;
    const int sub   = blk & 31;
    const int sid   = sub >> 4;          // 0: A_bar, 1: deltaB_x
    const int chunk = sub & 15;
    const int tid   = threadIdx.x;
    const int n4    = tid & 3;
    const int dloc  = tid >> 2;
    const int d     = (chunk << 6) + dloc;

    const float sd = ws[bl * WS_STRIDE + 32];
    const v4f   Bv = *(const v4f*)(ws + bl * WS_STRIDE + (n4 << 2));
    const float dp = delta_param[d];
    const v4f   Av = *(const v4f*)(A + (size_t)d * N_DIM + (n4 << 2));
    const float xv = x[(size_t)bl * D_DIM + d];

    // Delta = softplus(sd + delta_param[d]) = max(z,0) + log(1 + exp(-|z|))
    const float z     = sd + dp;
    const float e     = __expf(-fabsf(z));                  // v_exp_f32
    const float Delta = fmaxf(z, 0.0f) + __logf(1.0f + e);  // v_log_f32
    const float dx    = Delta * xv;

    v4f val;
    if (sid == 0) {
        #pragma unroll
        for (int i = 0; i < 4; ++i)
            val[i] = __expf(Delta * Av[i]);               // A_bar = exp(dA)
    } else {
        #pragma unroll
        for (int i = 0; i < 4; ++i) {
            const float dA = Delta * Av[i];
            const float ab = __expf(dA);
            const float em = ab - 1.0f;
            const float r_big = em * __builtin_amdgcn_rcpf(dA);   // v_rcp_f32
            // (e^u - 1)/u = 1 + u/2 + u^2/6 + u^3/24 + u^4/120 + u^5/720
            const float r_small =
                fmaf(dA, fmaf(dA, fmaf(dA, fmaf(dA, fmaf(dA,
                    1.3888889e-3f,   // 1/720
                    8.3333333e-3f),  // 1/120
                    4.1666667e-2f),  // 1/24
                    1.6666667e-1f),  // 1/6
                    0.5f), 1.0f);
            const float ratio = (fabsf(dA) < 0.5f) ? r_small : r_big;
            val[i] = ratio * Bv[i] * dx;    // (A_bar-1)/dA * Delta*B * x
        }
    }

    const size_t base = ((size_t)bl * KTOT + d) * N_DIM + (n4 << 2)
                      + (size_t)sid * (D_DIM * N_DIM);
    __builtin_nontemporal_store(val, (v4f*)(out + base));
}

extern "C" void kernel_launch(void* const* d_in, const int* in_sizes, int n_in,
                              void* d_out, int out_size, void* d_ws, size_t ws_size,
                              hipStream_t stream)
{
    const float* x           = (const float*)d_in[0];
    const float* W_b         = (const float*)d_in[1];
    const float* W_c         = (const float*)d_in[2];
    const float* W_delta     = (const float*)d_in[3];
    const float* A           = (const float*)d_in[4];
    const float* delta_param = (const float*)d_in[5];
    float* out = (float*)d_out;
    float* ws  = (float*)d_ws;

    const int BL = in_sizes[0] / D_DIM;   // 4096 tokens

    proj_kernel<<<BL, 256, 0, stream>>>(x, W_b, W_c, W_delta, ws, out);
    ssm_kernel<<<BL * 32, 256, 0, stream>>>(x, A, delta_param, ws, out);
}

// Round 7
// 533.590 us; speedup vs baseline: 1.1056x; 1.1056x over previous
//
#include <hip/hip_runtime.h>
#include <cmath>

// Problem constants (B_SZ=2, L=2048, D=1024, N=16)
#define D_DIM 1024
#define N_DIM 16
#define KTOT  2049          // 2*D + 1 (concat axis)
#define WS_STRIDE 36        // per-(b,l) row in ws: B[16], C[16 unused], sd @32
#define TPB 4               // tokens per proj block

typedef float v4f __attribute__((ext_vector_type(4)));

// ---------------------------------------------------------------------------
// Kernel 1: projections, 4 tokens per block (grid = BL/4 = 1024).
// Rationale (round-6 post-mortem): at 1 token/block, each of 4096 blocks
// re-read the full 132 KB of W_b/W_c -> ~540 MB of L2 traffic ~ 17 µs.
// Amortizing W across 4 tokens cuts that to ~135 MB (~4 µs); per-token
// reduction cost is unchanged (4x shuffles per wave, 4x fewer blocks).
//   wave 0: B rows 0..7  (+ s_delta)      -> ws      (x4 tokens)
//   wave 1: B rows 8..15                  -> ws
//   wave 2: C rows 0..7                   -> out[.., k=2048, 0..7]
//   wave 3: C rows 8..15                  -> out[.., k=2048, 8..15]
// ---------------------------------------------------------------------------
__global__ __launch_bounds__(256) void proj_kernel(
    const float* __restrict__ x, const float* __restrict__ W_b,
    const float* __restrict__ W_c, const float* __restrict__ W_delta,
    float* __restrict__ ws, float* __restrict__ out)
{
    const int bl0  = blockIdx.x * TPB;
    const int tid  = threadIdx.x;
    const int wave = tid >> 6;
    const int lane = tid & 63;

    const float* Wbase = (wave < 2) ? W_b : W_c;
    const int rowbase  = (wave & 1) * 8;

    float acc[TPB][8];
    #pragma unroll
    for (int t = 0; t < TPB; ++t)
        #pragma unroll
        for (int r = 0; r < 8; ++r) acc[t][r] = 0.f;
    float sd[TPB] = {0.f, 0.f, 0.f, 0.f};

    #pragma unroll
    for (int i = 0; i < 4; ++i) {
        const int off = (lane + (i << 6)) << 2;      // float offset, 16B aligned
        v4f xv[TPB];
        #pragma unroll
        for (int t = 0; t < TPB; ++t)
            xv[t] = *(const v4f*)(x + (size_t)(bl0 + t) * D_DIM + off);

        #pragma unroll
        for (int r = 0; r < 8; ++r) {
            const v4f wv = *(const v4f*)(Wbase + (size_t)(rowbase + r) * D_DIM + off);
            #pragma unroll
            for (int t = 0; t < TPB; ++t) {
                acc[t][r] = fmaf(xv[t][0], wv[0], acc[t][r]);
                acc[t][r] = fmaf(xv[t][1], wv[1], acc[t][r]);
                acc[t][r] = fmaf(xv[t][2], wv[2], acc[t][r]);
                acc[t][r] = fmaf(xv[t][3], wv[3], acc[t][r]);
            }
        }
        if (wave == 0) {
            const v4f wv = *(const v4f*)(W_delta + off);
            #pragma unroll
            for (int t = 0; t < TPB; ++t) {
                sd[t] = fmaf(xv[t][0], wv[0], sd[t]);
                sd[t] = fmaf(xv[t][1], wv[1], sd[t]);
                sd[t] = fmaf(xv[t][2], wv[2], sd[t]);
                sd[t] = fmaf(xv[t][3], wv[3], sd[t]);
            }
        }
    }

    // full 64-lane xor-shuffle reduction (per token, per row)
    #pragma unroll
    for (int t = 0; t < TPB; ++t) {
        #pragma unroll
        for (int r = 0; r < 8; ++r) {
            #pragma unroll
            for (int m = 32; m >= 1; m >>= 1)
                acc[t][r] += __shfl_xor(acc[t][r], m, 64);
        }
    }
    if (wave == 0) {
        #pragma unroll
        for (int t = 0; t < TPB; ++t) {
            #pragma unroll
            for (int m = 32; m >= 1; m >>= 1)
                sd[t] += __shfl_xor(sd[t], m, 64);
        }
    }

    if (lane == 0) {
        if (wave < 2) {
            #pragma unroll
            for (int t = 0; t < TPB; ++t) {
                float* dst = ws + (size_t)(bl0 + t) * WS_STRIDE + rowbase;
                #pragma unroll
                for (int r = 0; r < 8; ++r) dst[r] = acc[t][r];
                if (wave == 0) ws[(size_t)(bl0 + t) * WS_STRIDE + 32] = sd[t];
            }
        } else {
            // C goes straight into the k = 2*D slot of the output
            #pragma unroll
            for (int t = 0; t < TPB; ++t) {
                float* dst = out + ((size_t)(bl0 + t) * KTOT + 2 * D_DIM) * N_DIM + rowbase;
                #pragma unroll
                for (int r = 0; r < 8; ++r) dst[r] = acc[t][r];
            }
        }
    }
}

// ---------------------------------------------------------------------------
// Kernel 2: the 537 MB elementwise expansion — round-1/2 structure (best
// measured; round-6's single-stream-per-block variant regressed 42 µs).
// 16 blocks per (b,l); thread = (dloc = tid>>2, n4 = tid&3); two NT float4
// stores per thread: A_bar at k=d, deltaB_x at k=D+d. Block writes two
// contiguous 4 KB bursts.
// Math is native-rate and branchless (softplus via v_exp/v_log; ratio via
// rcp for |dA|>=0.5 — same cancellation the fp32 reference has — and a
// 6-term Taylor for |dA|<0.5 where cancellation bites).
// ---------------------------------------------------------------------------
__global__ __launch_bounds__(256) void ssm_kernel(
    const float* __restrict__ x, const float* __restrict__ A,
    const float* __restrict__ delta_param, const float* __restrict__ ws,
    float* __restrict__ out)
{
    const int blk   = blockIdx.x;
    const int bl    = blk >> 4;
    const int chunk = blk & 15;
    const int tid   = threadIdx.x;
    const int n4    = tid & 3;
    const int dloc  = tid >> 2;
    const int d     = (chunk << 6) + dloc;

    const float sd = ws[bl * WS_STRIDE + 32];
    const v4f   Bv = *(const v4f*)(ws + bl * WS_STRIDE + (n4 << 2));
    const float dp = delta_param[d];
    const v4f   Av = *(const v4f*)(A + (size_t)d * N_DIM + (n4 << 2));
    const float xv = x[(size_t)bl * D_DIM + d];

    // Delta = softplus(sd + delta_param[d]) = max(z,0) + log(1 + exp(-|z|))
    const float z     = sd + dp;
    const float e     = __expf(-fabsf(z));                  // v_exp_f32
    const float Delta = fmaxf(z, 0.0f) + __logf(1.0f + e);  // v_log_f32
    const float dx    = Delta * xv;

    v4f Abar, dbx;
    #pragma unroll
    for (int i = 0; i < 4; ++i) {
        const float dA = Delta * Av[i];
        const float ab = __expf(dA);                  // A_bar = exp(dA)
        const float em = ab - 1.0f;
        const float r_big = em * __builtin_amdgcn_rcpf(dA);   // v_rcp_f32
        // (e^u - 1)/u = 1 + u/2 + u^2/6 + u^3/24 + u^4/120 + u^5/720
        const float r_small =
            fmaf(dA, fmaf(dA, fmaf(dA, fmaf(dA, fmaf(dA,
                1.3888889e-3f,   // 1/720
                8.3333333e-3f),  // 1/120
                4.1666667e-2f),  // 1/24
                1.6666667e-1f),  // 1/6
                0.5f), 1.0f);
        const float ratio = (fabsf(dA) < 0.5f) ? r_small : r_big;
        Abar[i] = ab;
        dbx[i]  = ratio * Bv[i] * dx;   // (A_bar-1)/dA * Delta*B * x
    }

    const size_t base = ((size_t)bl * KTOT + d) * N_DIM + (n4 << 2);
    __builtin_nontemporal_store(Abar, (v4f*)(out + base));
    __builtin_nontemporal_store(dbx,  (v4f*)(out + base + (size_t)D_DIM * N_DIM));
}

extern "C" void kernel_launch(void* const* d_in, const int* in_sizes, int n_in,
                              void* d_out, int out_size, void* d_ws, size_t ws_size,
                              hipStream_t stream)
{
    const float* x           = (const float*)d_in[0];
    const float* W_b         = (const float*)d_in[1];
    const float* W_c         = (const float*)d_in[2];
    const float* W_delta     = (const float*)d_in[3];
    const float* A           = (const float*)d_in[4];
    const float* delta_param = (const float*)d_in[5];
    float* out = (float*)d_out;
    float* ws  = (float*)d_ws;

    const int BL = in_sizes[0] / D_DIM;   // 4096 tokens

    proj_kernel<<<BL / TPB, 256, 0, stream>>>(x, W_b, W_c, W_delta, ws, out);
    ssm_kernel<<<BL * 16, 256, 0, stream>>>(x, A, delta_param, ws, out);
}